// Round 3
// baseline (301.156 us; speedup 1.0000x reference)
//
#include <hip/hip_runtime.h>
#include <hip/hip_bf16.h>
#include <stdint.h>

// EuclideanDeconf: x[B,D] fp32, W[C,D] fp32 -> out[B,C] fp32
// out = (2/D)*x.W^T - ||x||^2/D - ||w||^2/D
#define B_ROWS 16384
#define D_DIM  1024
#define C_DIM  2048
#define MT_TOT (B_ROWS / 16)   // 1024 m-tiles
#define NT_TOT (C_DIM  / 16)   // 128  n-tiles
#define KT_TOT (D_DIM  / 32)   // 32   k-steps

typedef short bf16x8 __attribute__((ext_vector_type(8)));   // 8 bf16 = 4 VGPRs
typedef float f32x4  __attribute__((ext_vector_type(4)));

// ---------------------------------------------------------------------------
// pack_norm: fp32 -> bf16 packed in MFMA fragment order + row norms.
// Packed layout: chunk (tile, kt) = 1 KB = 64 lanes x 16 B, lane l holds
// row = tile*16 + (l&15), k = kt*32 + (l>>4)*8 .. +7  (the exact A/B operand
// layout of mfma_f32_16x16x32_bf16, verified by R1/R2 passing kernels).
// One wave per chunk. Norms via per-wave partial + atomicAdd (x2/w2 zeroed
// by hipMemsetAsync in kernel_launch).
// ---------------------------------------------------------------------------
__global__ __launch_bounds__(256) void pack_norm(
        const float* __restrict__ x, const float* __restrict__ W,
        ushort* __restrict__ Apk, ushort* __restrict__ Bpk,
        float* __restrict__ x2, float* __restrict__ w2) {
    int chunk = blockIdx.x * 4 + (threadIdx.x >> 6);
    const int lane = threadIdx.x & 63;
    const int XCH = MT_TOT * KT_TOT;            // 32768 x-chunks
    const float* src; ushort* dst; float* norm;
    if (chunk < XCH) { src = x; dst = Apk; norm = x2; }
    else             { src = W; dst = Bpk; norm = w2; chunk -= XCH; }
    const int tile = chunk >> 5;                // /KT_TOT
    const int kt   = chunk & 31;

    const int row = tile * 16 + (lane & 15);
    const int k0  = kt * 32 + (lane >> 4) * 8;
    const float4 v0 = *(const float4*)(src + (size_t)row * D_DIM + k0);
    const float4 v1 = *(const float4*)(src + (size_t)row * D_DIM + k0 + 4);
    float s = v0.x*v0.x + v0.y*v0.y + v0.z*v0.z + v0.w*v0.w
            + v1.x*v1.x + v1.y*v1.y + v1.z*v1.z + v1.w*v1.w;

    ushort u[8]; __hip_bfloat16 h;
    h = __float2bfloat16(v0.x); u[0] = *(const ushort*)&h;
    h = __float2bfloat16(v0.y); u[1] = *(const ushort*)&h;
    h = __float2bfloat16(v0.z); u[2] = *(const ushort*)&h;
    h = __float2bfloat16(v0.w); u[3] = *(const ushort*)&h;
    h = __float2bfloat16(v1.x); u[4] = *(const ushort*)&h;
    h = __float2bfloat16(v1.y); u[5] = *(const ushort*)&h;
    h = __float2bfloat16(v1.z); u[6] = *(const ushort*)&h;
    h = __float2bfloat16(v1.w); u[7] = *(const ushort*)&h;
    *(bf16x8*)(dst + ((size_t)chunk * 64 + lane) * 8) = *(const bf16x8*)u;

    // combine the 4 quads of each row, then 16 atomics (lanes 0-15)
    s += __shfl_xor(s, 16, 64);
    s += __shfl_xor(s, 32, 64);
    if (lane < 16) atomicAdd(norm + tile * 16 + lane, s * (1.0f / (float)D_DIM));
}

// ---------------------------------------------------------------------------
// gemm_flat: zero-LDS, zero-barrier GEMM on pre-packed fragments.
// Block 128x128 (4 waves, 2x2, wave tile 64x64 = 4x4 of 16x16x32 MFMA).
// Per k-step: 8 coalesced global_load_dwordx4 (frags straight to VGPR) +
// 16 MFMAs; 2-deep manual ping-pong keeps next step's loads in flight
// during current MFMAs — no s_barrier, no vmcnt(0) drain anywhere.
// XCD slab: 256 consecutive-dispatch blocks = 16 mTile-groups x all n.
// Epilogue: out = acc*(2/D) - x2[row] - w2[col]  (C/D layout per m89).
// ---------------------------------------------------------------------------
__global__ __launch_bounds__(256, 3) void gemm_flat(
        const ushort* __restrict__ Apk, const ushort* __restrict__ Bpk,
        const float* __restrict__ x2, const float* __restrict__ w2,
        float* __restrict__ out) {
    const int tid  = threadIdx.x;
    const int lane = tid & 63;
    const int wv   = tid >> 6;

    const int wid = (blockIdx.x & 7) * 256 + (blockIdx.x >> 3);  // XCD slab
    const int bm  = wid >> 4;          // [0,128)
    const int bn  = wid & 15;          // [0,16)
    const int mT0 = bm * 8 + (wv >> 1) * 4;    // wave's first m-tile
    const int nT0 = bn * 8 + (wv & 1) * 4;     // wave's first n-tile

    // lane's 16B slot within every 1KB fragment chunk
    const ushort* aP = Apk + ((size_t)mT0 * KT_TOT) * 512 + lane * 8;
    const ushort* bP = Bpk + ((size_t)nT0 * KT_TOT) * 512 + lane * 8;

    f32x4 acc[4][4];
    #pragma unroll
    for (int mi = 0; mi < 4; ++mi)
        #pragma unroll
        for (int ni = 0; ni < 4; ++ni)
            acc[mi][ni] = (f32x4){0.f, 0.f, 0.f, 0.f};

    bf16x8 aC[4], bC[4], aN[4], bN[4];

    #pragma unroll
    for (int i = 0; i < 4; ++i) {
        aC[i] = *(const bf16x8*)(aP + i * (KT_TOT * 512));
        bC[i] = *(const bf16x8*)(bP + i * (KT_TOT * 512));
    }

    #pragma unroll 4
    for (int kt = 0; kt < KT_TOT; kt += 2) {
        const int k1 = kt + 1;                       // always < KT_TOT (KT even)
        const int k2 = (kt + 2 < KT_TOT) ? kt + 2 : KT_TOT - 1;
        // prefetch kt+1, compute kt
        #pragma unroll
        for (int i = 0; i < 4; ++i) {
            aN[i] = *(const bf16x8*)(aP + i * (KT_TOT * 512) + k1 * 512);
            bN[i] = *(const bf16x8*)(bP + i * (KT_TOT * 512) + k1 * 512);
        }
        #pragma unroll
        for (int mi = 0; mi < 4; ++mi)
            #pragma unroll
            for (int ni = 0; ni < 4; ++ni)
                acc[mi][ni] = __builtin_amdgcn_mfma_f32_16x16x32_bf16(
                    aC[mi], bC[ni], acc[mi][ni], 0, 0, 0);
        // prefetch kt+2, compute kt+1
        #pragma unroll
        for (int i = 0; i < 4; ++i) {
            aC[i] = *(const bf16x8*)(aP + i * (KT_TOT * 512) + k2 * 512);
            bC[i] = *(const bf16x8*)(bP + i * (KT_TOT * 512) + k2 * 512);
        }
        #pragma unroll
        for (int mi = 0; mi < 4; ++mi)
            #pragma unroll
            for (int ni = 0; ni < 4; ++ni)
                acc[mi][ni] = __builtin_amdgcn_mfma_f32_16x16x32_bf16(
                    aN[mi], bN[ni], acc[mi][ni], 0, 0, 0);
    }

    // ---- epilogue: C/D layout col=lane&15, row=(lane>>4)*4+reg (m89) ----
    const float scale = 2.0f / (float)D_DIM;
    const int rsel = lane & 15;
    const int quad = lane >> 4;
    const int row0 = mT0 * 16 + quad * 4;
    const int col0 = nT0 * 16 + rsel;

    float x2r[4][4];
    #pragma unroll
    for (int mi = 0; mi < 4; ++mi)
        #pragma unroll
        for (int r = 0; r < 4; ++r)
            x2r[mi][r] = x2[row0 + mi * 16 + r];

    #pragma unroll
    for (int ni = 0; ni < 4; ++ni) {
        const int c = col0 + ni * 16;
        const float wc = w2[c];
        #pragma unroll
        for (int mi = 0; mi < 4; ++mi) {
            #pragma unroll
            for (int r = 0; r < 4; ++r) {
                const int rr = row0 + mi * 16 + r;
                out[(size_t)rr * C_DIM + c] = acc[mi][ni][r] * scale - x2r[mi][r] - wc;
            }
        }
    }
}

// ---------------------------------------------------------------------------
extern "C" void kernel_launch(void* const* d_in, const int* in_sizes, int n_in,
                              void* d_out, int out_size, void* d_ws, size_t ws_size,
                              hipStream_t stream) {
    const float* x = (const float*)d_in[0];   // [B, D] fp32
    const float* W = (const float*)d_in[1];   // [C, D] fp32
    float* out = (float*)d_out;               // [B, C] fp32

    // ws: Apk (32 MB bf16 packed) | Bpk (4 MB) | x2 (64 KB) | w2 (8 KB)
    char* ws = (char*)d_ws;
    ushort* Apk = (ushort*)ws;
    ushort* Bpk = (ushort*)(ws + (size_t)B_ROWS * D_DIM * sizeof(ushort));
    float*  x2  = (float*)(ws + (size_t)(B_ROWS + C_DIM) * D_DIM * sizeof(ushort));
    float*  w2  = x2 + B_ROWS;

    hipMemsetAsync(x2, 0, (B_ROWS + C_DIM) * sizeof(float), stream);

    // 32768 x-chunks + 4096 W-chunks, one wave each, 4 waves/block
    pack_norm<<<(MT_TOT * KT_TOT + NT_TOT * KT_TOT) / 4, 256, 0, stream>>>(
        x, W, Apk, Bpk, x2, w2);

    gemm_flat<<<(B_ROWS / 128) * (C_DIM / 128), 256, 0, stream>>>(
        Apk, Bpk, x2, w2, out);
}

// Round 4
// 251.812 us; speedup vs baseline: 1.1960x; 1.1960x over previous
//
#include <hip/hip_runtime.h>
#include <hip/hip_bf16.h>
#include <stdint.h>

// EuclideanDeconf: x[B,D] fp32, W[C,D] fp32 -> out[B,C] fp32
// out = (2/D)*x.W^T - ||x||^2/D - ||w||^2/D
#define B_ROWS 16384
#define D_DIM  1024
#define C_DIM  2048
#define MT_TOT (B_ROWS / 16)   // 1024 m-tiles
#define NT_TOT (C_DIM  / 16)   // 128  n-tiles
#define KT_TOT (D_DIM  / 32)   // 32   k-steps of K=32

typedef short bf16x8 __attribute__((ext_vector_type(8)));   // 8 bf16 = 4 VGPRs
typedef float f32x4  __attribute__((ext_vector_type(4)));

// ---------------------------------------------------------------------------
// pack_norm (verified R3): fp32 -> bf16 packed in MFMA fragment order + norms.
// Chunk (tile, kt) = 1 KB = 64 lanes x 16 B; lane l holds row = tile*16+(l&15),
// k = kt*32 + (l>>4)*8 .. +7 — the exact A/B operand layout of
// mfma_f32_16x16x32_bf16. One wave per chunk; norms via atomicAdd.
// ---------------------------------------------------------------------------
__global__ __launch_bounds__(256) void pack_norm(
        const float* __restrict__ x, const float* __restrict__ W,
        ushort* __restrict__ Apk, ushort* __restrict__ Bpk,
        float* __restrict__ x2, float* __restrict__ w2) {
    int chunk = blockIdx.x * 4 + (threadIdx.x >> 6);
    const int lane = threadIdx.x & 63;
    const int XCH = MT_TOT * KT_TOT;            // 32768 x-chunks
    const float* src; ushort* dst; float* norm;
    if (chunk < XCH) { src = x; dst = Apk; norm = x2; }
    else             { src = W; dst = Bpk; norm = w2; chunk -= XCH; }
    const int tile = chunk >> 5;                // /KT_TOT
    const int kt   = chunk & 31;

    const int row = tile * 16 + (lane & 15);
    const int k0  = kt * 32 + (lane >> 4) * 8;
    const float4 v0 = *(const float4*)(src + (size_t)row * D_DIM + k0);
    const float4 v1 = *(const float4*)(src + (size_t)row * D_DIM + k0 + 4);
    float s = v0.x*v0.x + v0.y*v0.y + v0.z*v0.z + v0.w*v0.w
            + v1.x*v1.x + v1.y*v1.y + v1.z*v1.z + v1.w*v1.w;

    ushort u[8]; __hip_bfloat16 h;
    h = __float2bfloat16(v0.x); u[0] = *(const ushort*)&h;
    h = __float2bfloat16(v0.y); u[1] = *(const ushort*)&h;
    h = __float2bfloat16(v0.z); u[2] = *(const ushort*)&h;
    h = __float2bfloat16(v0.w); u[3] = *(const ushort*)&h;
    h = __float2bfloat16(v1.x); u[4] = *(const ushort*)&h;
    h = __float2bfloat16(v1.y); u[5] = *(const ushort*)&h;
    h = __float2bfloat16(v1.z); u[6] = *(const ushort*)&h;
    h = __float2bfloat16(v1.w); u[7] = *(const ushort*)&h;
    *(bf16x8*)(dst + ((size_t)chunk * 64 + lane) * 8) = *(const bf16x8*)u;

    s += __shfl_xor(s, 16, 64);
    s += __shfl_xor(s, 32, 64);
    if (lane < 16) atomicAdd(norm + tile * 16 + lane, s * (1.0f / (float)D_DIM));
}

// ---------------------------------------------------------------------------
// gemm_pklds: LDS-shared GEMM on pre-packed fragments (m97 structure, but
// all addressing is linear: staging reads contiguous 1 KB chunks, fragment
// ds_read_b128s use ONE base VGPR + immediate offsets).
// Block 128x128, 4 waves 2x2 (wave tile 64x64 = 4x4 of 16x16x32), BK=64
// (2 k-steps per barrier pair). LDS = 16 A-chunks + 16 B-chunks = 32 KB,
// chunk slot (tile*2 + ks); contiguous lane*16B -> natively conflict-free.
// Waves 0-1 stage A (8 chunks each), waves 2-3 stage B.
// XCD slab remap for A-tile L2 locality (R2, FETCH 139->82 MB).
// Epilogue: out = acc*(2/D) - x2[row] - w2[col]  (C/D layout per m89).
// ---------------------------------------------------------------------------
__global__ __launch_bounds__(256, 3) void gemm_pklds(
        const ushort* __restrict__ Apk, const ushort* __restrict__ Bpk,
        const float* __restrict__ x2, const float* __restrict__ w2,
        float* __restrict__ out) {
    __shared__ ushort As[16 * 512];   // 16 KB: A chunks, slot = tile*2 + ks
    __shared__ ushort Bs[16 * 512];   // 16 KB

    const int tid  = threadIdx.x;
    const int lane = tid & 63;
    const int wv   = tid >> 6;

    const int wid = (blockIdx.x & 7) * 256 + (blockIdx.x >> 3);  // XCD slab
    const int bm  = wid >> 4;          // [0,128)
    const int bn  = wid & 15;          // [0,16)

    // staging source bases (ushort units); chunk (tile,kt) at (tile*KT+kt)*512
    const ushort* aSrc = Apk + ((size_t)(bm * 8) * KT_TOT) * 512 + lane * 8;
    const ushort* bSrc = Bpk + ((size_t)(bn * 8) * KT_TOT) * 512 + lane * 8;

    // fragment-read bases: one VGPR each, all 8 reads via immediate offsets
    const ushort* aRd = As + (wv >> 1) * 4 * 1024 + lane * 8;  // tile = (wv>>1)*4 + mi
    const ushort* bRd = Bs + (wv & 1) * 4 * 1024 + lane * 8;   // tile = (wv&1)*4 + ni

    f32x4 acc[4][4];
    #pragma unroll
    for (int mi = 0; mi < 4; ++mi)
        #pragma unroll
        for (int ni = 0; ni < 4; ++ni)
            acc[mi][ni] = (f32x4){0.f, 0.f, 0.f, 0.f};

    for (int kt = 0; kt < KT_TOT; kt += 2) {
        // ---- stage 32 chunks (16 A + 16 B), 8 per wave, wave-uniform LDS base ----
        if (wv < 2) {
            #pragma unroll
            for (int r = 0; r < 8; ++r) {
                const int c    = wv * 8 + r;          // A chunk slot [0,16)
                const int tile = c >> 1, ks = c & 1;
                __builtin_amdgcn_global_load_lds(
                    (const __attribute__((address_space(1))) void*)(
                        aSrc + ((size_t)tile * KT_TOT + kt + ks) * 512),
                    (__attribute__((address_space(3))) void*)(As + c * 512), 16, 0, 0);
            }
        } else {
            #pragma unroll
            for (int r = 0; r < 8; ++r) {
                const int c    = (wv - 2) * 8 + r;    // B chunk slot [0,16)
                const int tile = c >> 1, ks = c & 1;
                __builtin_amdgcn_global_load_lds(
                    (const __attribute__((address_space(1))) void*)(
                        bSrc + ((size_t)tile * KT_TOT + kt + ks) * 512),
                    (__attribute__((address_space(3))) void*)(Bs + c * 512), 16, 0, 0);
            }
        }
        __syncthreads();

        // ---- compute: 2 k-steps x 16 MFMAs; reads = base + imm offset only ----
        #pragma unroll
        for (int ks = 0; ks < 2; ++ks) {
            bf16x8 a[4], b[4];
            #pragma unroll
            for (int mi = 0; mi < 4; ++mi)
                a[mi] = *(const bf16x8*)(aRd + mi * 1024 + ks * 512);
            #pragma unroll
            for (int ni = 0; ni < 4; ++ni)
                b[ni] = *(const bf16x8*)(bRd + ni * 1024 + ks * 512);
            #pragma unroll
            for (int mi = 0; mi < 4; ++mi)
                #pragma unroll
                for (int ni = 0; ni < 4; ++ni)
                    acc[mi][ni] = __builtin_amdgcn_mfma_f32_16x16x32_bf16(
                        a[mi], b[ni], acc[mi][ni], 0, 0, 0);
        }
        __syncthreads();
    }

    // ---- epilogue: C/D layout col=lane&15, row=(lane>>4)*4+reg (m89) ----
    const float scale = 2.0f / (float)D_DIM;
    const int rsel = lane & 15;
    const int quad = lane >> 4;
    const int mT0  = bm * 8 + (wv >> 1) * 4;
    const int nT0  = bn * 8 + (wv & 1) * 4;
    const int row0 = mT0 * 16 + quad * 4;
    const int col0 = nT0 * 16 + rsel;

    float x2r[4][4];
    #pragma unroll
    for (int mi = 0; mi < 4; ++mi)
        #pragma unroll
        for (int r = 0; r < 4; ++r)
            x2r[mi][r] = x2[row0 + mi * 16 + r];

    #pragma unroll
    for (int ni = 0; ni < 4; ++ni) {
        const int c = col0 + ni * 16;
        const float wc = w2[c];
        #pragma unroll
        for (int mi = 0; mi < 4; ++mi) {
            #pragma unroll
            for (int r = 0; r < 4; ++r) {
                const int rr = row0 + mi * 16 + r;
                out[(size_t)rr * C_DIM + c] = acc[mi][ni][r] * scale - x2r[mi][r] - wc;
            }
        }
    }
}

// ---------------------------------------------------------------------------
extern "C" void kernel_launch(void* const* d_in, const int* in_sizes, int n_in,
                              void* d_out, int out_size, void* d_ws, size_t ws_size,
                              hipStream_t stream) {
    const float* x = (const float*)d_in[0];   // [B, D] fp32
    const float* W = (const float*)d_in[1];   // [C, D] fp32
    float* out = (float*)d_out;               // [B, C] fp32

    // ws: Apk (32 MB bf16 packed) | Bpk (4 MB) | x2 (64 KB) | w2 (8 KB)
    char* ws = (char*)d_ws;
    ushort* Apk = (ushort*)ws;
    ushort* Bpk = (ushort*)(ws + (size_t)B_ROWS * D_DIM * sizeof(ushort));
    float*  x2  = (float*)(ws + (size_t)(B_ROWS + C_DIM) * D_DIM * sizeof(ushort));
    float*  w2  = x2 + B_ROWS;

    hipMemsetAsync(x2, 0, (B_ROWS + C_DIM) * sizeof(float), stream);

    pack_norm<<<(MT_TOT * KT_TOT + NT_TOT * KT_TOT) / 4, 256, 0, stream>>>(
        x, W, Apk, Bpk, x2, w2);

    gemm_pklds<<<(B_ROWS / 128) * (C_DIM / 128), 256, 0, stream>>>(
        Apk, Bpk, x2, w2, out);
}